// Round 10
// baseline (133.400 us; speedup 1.0000x reference)
//
#include <hip/hip_runtime.h>
#include <hip/hip_bf16.h>

// Flash-attention fwd, block-causal packed docs. fp32 HBM, bf16 MFMA.
// B=1, H=8, D=128. 4 waves/block, BR=64, BC=64, grid 512, 2 blocks/CU.
// R9 skeleton: register-prefetch pipeline, double-buffered LDS, 1 barrier/tile,
// balanced qb pairing, launch_bounds(256,2) (NOT 3 -> spills, R8).
// R10: S computed TRANSPOSED (mfma operands swapped: A=K,B=Q) so softmax is
// per-lane (col=l16=q): 2 shuffles instead of 16, scalar stats; P written to
// q-major LDS as 4x b64 packed writes (was 16x b16). PV/O layout unchanged.

#define HD 128
#define BR 64
#define BC 64
#define KSTR 136     // bf16 per sK row: 272 B
#define VSTR 33      // dwords per sVT row (32 key-pair dwords + 1 pad; odd)
#define PSTR 68      // bf16 per sP row: 136 B

typedef __attribute__((ext_vector_type(8))) short short8;
typedef __attribute__((ext_vector_type(4))) float floatx4;

__device__ inline unsigned packbf2(float lo, float hi) {
    __hip_bfloat162 h2 = __float22bfloat162_rn(make_float2(lo, hi));
    return *reinterpret_cast<unsigned*>(&h2);   // low16 = lo, high16 = hi
}
__device__ inline short bfs(float f) {
    __hip_bfloat16 b = __float2bfloat16(f);
    return *reinterpret_cast<short*>(&b);
}

union F4 { float4 v; float f[4]; };

__global__ __launch_bounds__(256, 2) void fa_fwd(
    const float* __restrict__ Q,
    const float* __restrict__ K,
    const float* __restrict__ V,
    const int* __restrict__ cu_seqlens, int n_cu,
    float* __restrict__ O,
    int S)
{
    __shared__ alignas(16) __hip_bfloat16 sK[2][BC * KSTR];   // 34816 B
    __shared__ alignas(16) unsigned int   sVT[2][HD * VSTR];  // 33792 B
    __shared__ alignas(16) __hip_bfloat16 sP[4][16 * PSTR];   //  8704 B

    const int tid  = threadIdx.x;
    const int wave = tid >> 6;
    const int lane = tid & 63;
    const int quad = lane >> 4;
    const int l16  = lane & 15;

    // K staging coords
    const int dblk = tid & 31;      // d = 4*dblk
    const int trow = tid >> 5;      // 0..7
    // V staging coords: one d-row per thread
    const int vd    = tid & 127;
    const int vhalf = tid >> 7;

    const int nqb = S / BR;
    const int h   = blockIdx.x & 7;
    const int g   = (int)(blockIdx.x >> 3);
    int qb;
    if (nqb == 64) {
        // balanced pairing: co-resident blocks g, g+32 have ntiles summing 17
        if (g < 32) qb = (g >> 4) * 16 + (15 - (g & 15));        // docs 0,1 desc
        else        qb = 32 + (((g - 32) >> 4) * 16) + (g & 15); // docs 2,3 asc
    } else {
        qb = nqb - 1 - g;
    }
    const int q0  = qb * BR;
    const int qw  = q0 + wave * 16;

    const size_t hoff = (size_t)h * S * HD;
    const float* Qh = Q + hoff;
    const float* Kh = K + hoff;
    const float* Vh = V + hoff;
    float*       Oh = O + hoff;

    // ---- per-lane doc start (this lane's q column = qw + l16) ----
    const int qv = qw + l16;
    int ds = 0;
    for (int i = 0; i < n_cu; ++i) {
        int c = cu_seqlens[i];
        if (c <= qv) ds = c;
    }
    int blk_ds = 0;
    for (int i = 0; i < n_cu; ++i) {
        int c = cu_seqlens[i];
        if (c <= q0) blk_ds = c;
    }
    const int k_begin = blk_ds & ~(BC - 1);
    const int ntiles  = (q0 + BR - 1 - k_begin) / BC + 1;   // block-uniform

    // ---- Q B-frags: B[n=q=l16][k=d=ks*32+quad*8+j] ----
    short8 aq[4];
    {
        const float* qp = Qh + (size_t)(qw + l16) * HD + quad * 8;
        #pragma unroll
        for (int ks = 0; ks < 4; ++ks) {
            float4 a0 = *(const float4*)(qp + ks * 32);
            float4 a1 = *(const float4*)(qp + ks * 32 + 4);
            short8 a;
            a[0] = bfs(a0.x); a[1] = bfs(a0.y); a[2] = bfs(a0.z); a[3] = bfs(a0.w);
            a[4] = bfs(a1.x); a[5] = bfs(a1.y); a[6] = bfs(a1.z); a[7] = bfs(a1.w);
            aq[ks] = a;
        }
    }

    floatx4 oacc[8];
    #pragma unroll
    for (int dt = 0; dt < 8; ++dt) oacc[dt] = (floatx4){0.f, 0.f, 0.f, 0.f};
    float m_s = -1e30f, l_s = 0.f;   // per-lane scalar stats for q = qw+l16

    const float sl = 0.08838834764831845f * 1.4426950408889634f;

    // ---- pipeline registers ----
    F4 kf[8];
    float vf[32];

    auto issue_loads = [&](int kt) {
        const float* kb = Kh + (size_t)kt * HD + 4 * dblk;
        #pragma unroll
        for (int p = 0; p < 8; ++p)
            kf[p].v = *(const float4*)(kb + (size_t)(trow + 8 * p) * HD);
        const float* vb = Vh + (size_t)(kt + vhalf * 32) * HD + vd;
        #pragma unroll
        for (int kk = 0; kk < 32; ++kk)
            vf[kk] = vb[(size_t)kk * HD];
    };

    auto write_tiles = [&](int buf) {
        #pragma unroll
        for (int p = 0; p < 8; ++p) {
            uint2 kw;
            kw.x = packbf2(kf[p].f[0], kf[p].f[1]);
            kw.y = packbf2(kf[p].f[2], kf[p].f[3]);
            *(uint2*)(&sK[buf][(trow + 8 * p) * KSTR + 4 * dblk]) = kw;
        }
        unsigned* dst = &sVT[buf][vd * VSTR + vhalf * 16];
        #pragma unroll
        for (int kp = 0; kp < 16; ++kp)
            dst[kp] = packbf2(vf[2 * kp], vf[2 * kp + 1]);
    };

    issue_loads(k_begin);

    __hip_bfloat16* pbuf = &sP[wave][0];

    for (int it = 0; it < ntiles; ++it) {
        const int kt  = k_begin + it * BC;
        const int buf = it & 1;

        write_tiles(buf);
        __syncthreads();                         // one barrier per tile

        if (it + 1 < ntiles) issue_loads(kt + BC);

        // ---- S^T = K Q^T : C col = l16 = q, row = quad*4+r = key ----
        floatx4 sc[4];
        #pragma unroll
        for (int ct = 0; ct < 4; ++ct) {
            if (kt + ct * 16 <= qw + 15) {       // wave-uniform causal skip
                floatx4 c = (floatx4){0.f, 0.f, 0.f, 0.f};
                #pragma unroll
                for (int ks = 0; ks < 4; ++ks) {
                    short8 bk = *(const short8*)(&sK[buf][(ct * 16 + l16) * KSTR + ks * 32 + quad * 8]);
                    c = __builtin_amdgcn_mfma_f32_16x16x32_bf16(bk, aq[ks], c, 0, 0, 0);
                }
                #pragma unroll
                for (int r = 0; r < 4; ++r) {
                    const int key = kt + ct * 16 + quad * 4 + r;
                    const bool valid = (key <= qv) && (key >= ds);
                    float s = c[r] * sl;
                    c[r] = valid ? s : -1e30f;
                }
                sc[ct] = c;
            } else {
                sc[ct] = (floatx4){-1e30f, -1e30f, -1e30f, -1e30f};
            }
        }

        // ---- per-lane softmax (q = l16 column) ----
        float mx = -1e30f;
        #pragma unroll
        for (int ct = 0; ct < 4; ++ct)
            #pragma unroll
            for (int r = 0; r < 4; ++r)
                mx = fmaxf(mx, sc[ct][r]);
        mx = fmaxf(mx, __shfl_xor(mx, 16, 64));
        mx = fmaxf(mx, __shfl_xor(mx, 32, 64));
        const float mnew = fmaxf(m_s, mx);
        const float al   = exp2f(m_s - mnew);
        m_s = mnew;
        float ls = 0.f;
        #pragma unroll
        for (int ct = 0; ct < 4; ++ct) {
            #pragma unroll
            for (int r = 0; r < 4; ++r) {
                float e = exp2f(sc[ct][r] - mnew);
                sc[ct][r] = e;
                ls += e;
            }
        }
        l_s = l_s * al + ls;

        // broadcast al from lane l16=quad*4+r to this lane's O rows
        float alr[4];
        #pragma unroll
        for (int r = 0; r < 4; ++r)
            alr[r] = __shfl(al, quad * 4 + r, 64);
        #pragma unroll
        for (int dt = 0; dt < 8; ++dt) {
            #pragma unroll
            for (int r = 0; r < 4; ++r)
                oacc[dt][r] *= alr[r];
        }

        // ---- P: S^T C-layout -> q-major LDS (4x packed b64 writes) ----
        #pragma unroll
        for (int ct = 0; ct < 4; ++ct) {
            uint2 pw;
            pw.x = packbf2(sc[ct][0], sc[ct][1]);
            pw.y = packbf2(sc[ct][2], sc[ct][3]);
            *(uint2*)(&pbuf[l16 * PSTR + ct * 16 + quad * 4]) = pw;
        }

        // ---- O += P V (skip fully-masked 32-key halves) ----
        #pragma unroll
        for (int ks = 0; ks < 2; ++ks) {
            if (kt + ks * 32 <= qw + 15) {       // wave-uniform
                short8 ap = *(const short8*)(&pbuf[l16 * PSTR + ks * 32 + quad * 8]);
                #pragma unroll
                for (int dt = 0; dt < 8; ++dt) {
                    const unsigned* vp = &sVT[buf][(dt * 16 + l16) * VSTR + ks * 16 + quad * 4];
                    union { unsigned u[4]; short8 s; } cv;
                    cv.u[0] = vp[0]; cv.u[1] = vp[1]; cv.u[2] = vp[2]; cv.u[3] = vp[3];
                    oacc[dt] = __builtin_amdgcn_mfma_f32_16x16x32_bf16(ap, cv.s, oacc[dt], 0, 0, 0);
                }
            }
        }
    }

    // ---- epilogue: finish l reduction, broadcast to O rows, store ----
    l_s += __shfl_xor(l_s, 16, 64);
    l_s += __shfl_xor(l_s, 32, 64);
    #pragma unroll
    for (int r = 0; r < 4; ++r) {
        const float inv = 1.0f / __shfl(l_s, quad * 4 + r, 64);
        float* op = Oh + (size_t)(qw + quad * 4 + r) * HD;
        #pragma unroll
        for (int dt = 0; dt < 8; ++dt)
            op[dt * 16 + l16] = oacc[dt][r] * inv;
    }
}

extern "C" void kernel_launch(void* const* d_in, const int* in_sizes, int n_in,
                              void* d_out, int out_size, void* d_ws, size_t ws_size,
                              hipStream_t stream) {
    const float* q = (const float*)d_in[0];
    const float* k = (const float*)d_in[1];
    const float* v = (const float*)d_in[2];
    const int* cu = (const int*)d_in[3];
    const int n_cu = in_sizes[3];
    const int H = 8;
    const int S = in_sizes[0] / (H * HD);   // B=1
    float* out = (float*)d_out;

    dim3 grid(H * (S / BR));   // 512 blocks
    dim3 block(256);
    fa_fwd<<<grid, block, 0, stream>>>(q, k, v, cu, n_cu, out, S);
}